// Round 1
// baseline (1386.836 us; speedup 1.0000x reference)
//
#include <hip/hip_runtime.h>

#define N_NODES 50000
#define N_EDGES 600000
#define HC 256
#define NH 8

// ---------------------------------------------------------------- CSR build
__global__ void k_init_cnt(int* __restrict__ cnt) {
  int i = blockIdx.x * 256 + threadIdx.x;
  if (i < N_NODES) cnt[i] = 1;  // self-loop
}

__global__ void k_count(const int* __restrict__ dstE, int* __restrict__ cnt) {
  int e = blockIdx.x * 256 + threadIdx.x;
  if (e < N_EDGES) atomicAdd(&cnt[dstE[e]], 1);
}

__global__ void k_scan_bsum(const int* __restrict__ cnt, int* __restrict__ bsum) {
  __shared__ int sd[256];
  int i = blockIdx.x * 256 + threadIdx.x;
  sd[threadIdx.x] = (i < N_NODES) ? cnt[i] : 0;
  __syncthreads();
  for (int o = 128; o > 0; o >>= 1) {
    if (threadIdx.x < o) sd[threadIdx.x] += sd[threadIdx.x + o];
    __syncthreads();
  }
  if (threadIdx.x == 0) bsum[blockIdx.x] = sd[0];
}

__global__ void k_scan_offsets(int* __restrict__ bsum, int nb) {
  __shared__ int s[256];
  int t = threadIdx.x;
  int v = (t < nb) ? bsum[t] : 0;
  s[t] = v; __syncthreads();
  for (int o = 1; o < 256; o <<= 1) {
    int x = (t >= o) ? s[t - o] : 0;
    __syncthreads();
    s[t] += x;
    __syncthreads();
  }
  if (t < nb) bsum[t] = s[t] - v;  // exclusive
}

__global__ void k_scan_write(const int* __restrict__ cnt, const int* __restrict__ bsum,
                             int* __restrict__ rowptr, int* __restrict__ fillptr) {
  __shared__ int s[256];
  int t = threadIdx.x;
  int i = blockIdx.x * 256 + t;
  int v = (i < N_NODES) ? cnt[i] : 0;
  s[t] = v; __syncthreads();
  for (int o = 1; o < 256; o <<= 1) {
    int x = (t >= o) ? s[t - o] : 0;
    __syncthreads();
    s[t] += x;
    __syncthreads();
  }
  int excl = s[t] - v + bsum[blockIdx.x];
  if (i < N_NODES) {
    rowptr[i] = excl;
    fillptr[i] = excl;
    if (i == N_NODES - 1) rowptr[N_NODES] = excl + v;
  }
}

__global__ void k_fill(const int* __restrict__ srcE, const int* __restrict__ dstE,
                       int* __restrict__ fillptr, int* __restrict__ srcs) {
  int i = blockIdx.x * 256 + threadIdx.x;
  if (i < N_NODES) {
    int pos = atomicAdd(&fillptr[i], 1);
    srcs[pos] = i;                       // self-loop
  } else if (i < N_NODES + N_EDGES) {
    int e = i - N_NODES;
    int pos = atomicAdd(&fillptr[dstE[e]], 1);
    srcs[pos] = srcE[e];
  }
}

// ---------------------------------------------------------------- GEMM (fp32, N=256 fixed)
__launch_bounds__(256)
__global__ void k_gemm(const float* __restrict__ A, const float* __restrict__ W,
                       const float* __restrict__ bias, float* __restrict__ Out,
                       int M, int K) {
  __shared__ float As[16][68];  // transposed A tile, pad 68 -> 16B-aligned rows, 2-way banks
  __shared__ float Bs[16][64];
  int t = threadIdx.x;
  int bm = blockIdx.x * 64;
  int bn = blockIdx.y * 64;
  int tx = t & 15, ty = t >> 4;
  int arow = t >> 2, acol = (t & 3) << 2;
  int wrow = t >> 4, wcol = (t & 15) << 2;
  float acc[4][4] = {{0.f}};
  int gr = bm + arow;
  const float4* Arow = (gr < M) ? (const float4*)&A[(size_t)gr * K] : nullptr;
  for (int k0 = 0; k0 < K; k0 += 16) {
    float4 a4 = make_float4(0.f, 0.f, 0.f, 0.f);
    if (Arow) a4 = Arow[(k0 + acol) >> 2];
    As[acol + 0][arow] = a4.x;
    As[acol + 1][arow] = a4.y;
    As[acol + 2][arow] = a4.z;
    As[acol + 3][arow] = a4.w;
    *(float4*)&Bs[wrow][wcol] = *(const float4*)&W[(size_t)(k0 + wrow) * 256 + bn + wcol];
    __syncthreads();
#pragma unroll
    for (int kk = 0; kk < 16; kk++) {
      float4 av = *(const float4*)&As[kk][ty << 2];
      float4 bv = *(const float4*)&Bs[kk][tx << 2];
      acc[0][0] += av.x * bv.x; acc[0][1] += av.x * bv.y; acc[0][2] += av.x * bv.z; acc[0][3] += av.x * bv.w;
      acc[1][0] += av.y * bv.x; acc[1][1] += av.y * bv.y; acc[1][2] += av.y * bv.z; acc[1][3] += av.y * bv.w;
      acc[2][0] += av.z * bv.x; acc[2][1] += av.z * bv.y; acc[2][2] += av.z * bv.z; acc[2][3] += av.z * bv.w;
      acc[3][0] += av.w * bv.x; acc[3][1] += av.w * bv.y; acc[3][2] += av.w * bv.z; acc[3][3] += av.w * bv.w;
    }
    __syncthreads();
  }
  float4 bb = make_float4(0.f, 0.f, 0.f, 0.f);
  if (bias) bb = *(const float4*)&bias[bn + (tx << 2)];
#pragma unroll
  for (int i = 0; i < 4; i++) {
    int r = bm + (ty << 2) + i;
    if (r < M) {
      float4 o;
      o.x = acc[i][0] + bb.x; o.y = acc[i][1] + bb.y;
      o.z = acc[i][2] + bb.z; o.w = acc[i][3] + bb.w;
      *(float4*)&Out[(size_t)r * 256 + bn + (tx << 2)] = o;
    }
  }
}

// ---------------------------------------------------------------- attention logits a_s, a_d
__launch_bounds__(256)
__global__ void k_att(const float* __restrict__ B, const float* __restrict__ asrc,
                      const float* __restrict__ adst,
                      float* __restrict__ as_, float* __restrict__ ad_) {
  int wid = (blockIdx.x * 256 + threadIdx.x) >> 6;  // node
  int lane = threadIdx.x & 63;
  float4 h4 = *(const float4*)&B[(size_t)wid * 256 + (lane << 2)];
  float4 s4 = *(const float4*)&asrc[lane << 2];   // [8][32] flat == lane*4 mapping
  float4 d4 = *(const float4*)&adst[lane << 2];
  float vs = h4.x * s4.x + h4.y * s4.y + h4.z * s4.z + h4.w * s4.w;
  float vd = h4.x * d4.x + h4.y * d4.y + h4.z * d4.z + h4.w * d4.w;
  vs += __shfl_xor(vs, 1); vs += __shfl_xor(vs, 2); vs += __shfl_xor(vs, 4);
  vd += __shfl_xor(vd, 1); vd += __shfl_xor(vd, 2); vd += __shfl_xor(vd, 4);
  if ((lane & 7) == 0) {
    as_[wid * NH + (lane >> 3)] = vs;
    ad_[wid * NH + (lane >> 3)] = vd;
  }
}

// ---------------------------------------------------------------- softmax + aggregate (one wave / node)
__launch_bounds__(256)
__global__ void k_agg(const int* __restrict__ rowptr, const int* __restrict__ srcs,
                      const float* __restrict__ as_, const float* __restrict__ ad_,
                      const float* __restrict__ B, const float* __restrict__ gb,
                      float* __restrict__ C) {
  int n = (blockIdx.x * 256 + threadIdx.x) >> 6;
  int lane = threadIdx.x & 63;
  int beg = rowptr[n], end = rowptr[n + 1];
  int h = lane >> 3, j = lane & 7;      // head h for both phases and channel phase
  float ad_nh = ad_[n * NH + h];
  // phase 1: per-head max
  float mx = -1e30f;
  for (int k = beg + j; k < end; k += 8) {
    int s = srcs[k];
    float e = as_[s * NH + h] + ad_nh;
    e = e > 0.f ? e : 0.2f * e;
    mx = fmaxf(mx, e);
  }
  mx = fmaxf(mx, __shfl_xor(mx, 1));
  mx = fmaxf(mx, __shfl_xor(mx, 2));
  mx = fmaxf(mx, __shfl_xor(mx, 4));
  // phase 2: per-head sum of exp
  float sum = 0.f;
  for (int k = beg + j; k < end; k += 8) {
    int s = srcs[k];
    float e = as_[s * NH + h] + ad_nh;
    e = e > 0.f ? e : 0.2f * e;
    sum += __expf(e - mx);
  }
  sum += __shfl_xor(sum, 1); sum += __shfl_xor(sum, 2); sum += __shfl_xor(sum, 4);
  float inv = 1.f / (sum + 1e-16f);
  // phase 3: aggregate; lane covers channels lane*4..+3 (head = lane>>3, consistent)
  float4 acc = make_float4(0.f, 0.f, 0.f, 0.f);
  for (int k = beg; k < end; k++) {
    int s = srcs[k];
    float e = as_[s * NH + h] + ad_nh;
    e = e > 0.f ? e : 0.2f * e;
    float alpha = __expf(e - mx) * inv;
    float4 b4 = *(const float4*)&B[(size_t)s * 256 + (lane << 2)];
    acc.x += alpha * b4.x; acc.y += alpha * b4.y;
    acc.z += alpha * b4.z; acc.w += alpha * b4.w;
  }
  float4 g4 = *(const float4*)&gb[lane << 2];
  acc.x += g4.x; acc.y += g4.y; acc.z += g4.z; acc.w += g4.w;
  *(float4*)&C[(size_t)n * 256 + (lane << 2)] = acc;
}

// ---------------------------------------------------------------- batch norm
__global__ void k_bn_stats(const float* __restrict__ X, float* __restrict__ stats) {
  int c = threadIdx.x;  // 256 channels
  float s = 0.f, s2 = 0.f;
  for (int r = blockIdx.x; r < N_NODES; r += gridDim.x) {
    float v = X[(size_t)r * 256 + c];
    s += v; s2 += v * v;
  }
  atomicAdd(&stats[c], s);
  atomicAdd(&stats[256 + c], s2);
}

__global__ void k_bn_relu(float* __restrict__ X, const float* __restrict__ stats,
                          const float* __restrict__ g, const float* __restrict__ b) {
  size_t i = (size_t)blockIdx.x * 256 + threadIdx.x;
  int c = (int)(i & 255);
  const float invN = 1.f / (float)N_NODES;
  float mean = stats[c] * invN;
  float var = stats[256 + c] * invN - mean * mean;
  float sc = rsqrtf(var + 1e-5f) * g[c];
  float v = (X[i] - mean) * sc + b[c];
  X[i] = v > 0.f ? v : 0.f;
}

// ---------------------------------------------------------------- fused heads (one wave / node)
__launch_bounds__(256)
__global__ void k_final(const float* __restrict__ A, const float* __restrict__ R,
                        const float* __restrict__ eps,
                        const float* __restrict__ muW, const float* __restrict__ mub,
                        const float* __restrict__ lvW, const float* __restrict__ lvb,
                        const float* __restrict__ decW, const float* __restrict__ decb,
                        const float* __restrict__ auxW, const float* __restrict__ auxb,
                        float* __restrict__ out) {
  __shared__ float sh[4][256];
  __shared__ float shz[4][32];
  int w = threadIdx.x >> 6, lane = threadIdx.x & 63;
  int n = blockIdx.x * 4 + w;  // grid is exactly N/4: no partial blocks
  float4 a4 = *(const float4*)&A[(size_t)n * 256 + (lane << 2)];
  float4 r4 = *(const float4*)&R[(size_t)n * 256 + (lane << 2)];
  float4 h4 = make_float4(a4.x + r4.x, a4.y + r4.y, a4.z + r4.z, a4.w + r4.w);
  *(float4*)&sh[w][lane << 2] = h4;
  __syncthreads();
  int jj = lane & 31;
  const float* Wp = (lane < 32) ? muW : lvW;
  float acc = (lane < 32) ? mub[jj] : lvb[jj];
#pragma unroll 4
  for (int k = 0; k < 256; k++) acc += sh[w][k] * Wp[k * 32 + jj];
  float lvj = __shfl(acc, jj + 32);  // lanes<32 fetch their logvar partner
  if (lane < 32) {
    out[(size_t)N_NODES * 64 + (size_t)n * 32 + jj] = acc;  // mu
    float z = acc + eps[(size_t)n * 32 + jj] * __expf(0.5f * lvj);
    shz[w][jj] = z;
  } else {
    out[(size_t)N_NODES * 96 + (size_t)n * 32 + jj] = acc;  // logvar
  }
  __syncthreads();
  float o = decb[lane];
#pragma unroll
  for (int k = 0; k < 32; k++) o += shz[w][k] * decW[k * 64 + lane];
  out[(size_t)n * 64 + lane] = o;
  if (lane < 30) {
    float a = auxb[lane];
    for (int k = 0; k < 256; k++) a += sh[w][k] * auxW[k * 30 + lane];
    out[(size_t)N_NODES * 128 + (size_t)n * 30 + lane] = a;
  }
}

// ---------------------------------------------------------------- launch
extern "C" void kernel_launch(void* const* d_in, const int* in_sizes, int n_in,
                              void* d_out, int out_size, void* d_ws, size_t ws_size,
                              hipStream_t stream) {
  (void)in_sizes; (void)n_in; (void)out_size; (void)ws_size;
  const float* x    = (const float*)d_in[0];
  const float* eps  = (const float*)d_in[1];
  const int*   ei   = (const int*)d_in[2];
  const float* gW[3]   = {(const float*)d_in[3],  (const float*)d_in[9],  (const float*)d_in[15]};
  const float* gasrc[3] = {(const float*)d_in[4],  (const float*)d_in[10], (const float*)d_in[16]};
  const float* gadst[3] = {(const float*)d_in[5],  (const float*)d_in[11], (const float*)d_in[17]};
  const float* gbias[3] = {(const float*)d_in[6],  (const float*)d_in[12], (const float*)d_in[18]};
  const float* bng[3]  = {(const float*)d_in[7],  (const float*)d_in[13], (const float*)d_in[19]};
  const float* bnb[3]  = {(const float*)d_in[8],  (const float*)d_in[14], (const float*)d_in[20]};
  const float* resW = (const float*)d_in[21];
  const float* resb = (const float*)d_in[22];
  const float* muW  = (const float*)d_in[23];
  const float* mub  = (const float*)d_in[24];
  const float* lvW  = (const float*)d_in[25];
  const float* lvb  = (const float*)d_in[26];
  const float* decW = (const float*)d_in[27];
  const float* decb = (const float*)d_in[28];
  const float* auxW = (const float*)d_in[29];
  const float* auxb = (const float*)d_in[30];
  float* out = (float*)d_out;

  char* ws = (char*)d_ws;
  size_t off = 0;
  auto alloc = [&](size_t bytes) -> void* {
    void* p = ws + off;
    off += (bytes + 255) & ~(size_t)255;
    return p;
  };
  float* X0    = (float*)alloc((size_t)N_NODES * HC * 4);   // transformed features B
  float* X1    = (float*)alloc((size_t)N_NODES * HC * 4);   // layer output / next input
  float* Rr    = (float*)alloc((size_t)N_NODES * HC * 4);   // residual
  float* as_   = (float*)alloc((size_t)N_NODES * NH * 4);
  float* ad_   = (float*)alloc((size_t)N_NODES * NH * 4);
  float* stats = (float*)alloc(512 * 4);
  int* cnt     = (int*)alloc((size_t)N_NODES * 4);
  int* rowptr  = (int*)alloc((size_t)(N_NODES + 1) * 4);
  int* fillptr = (int*)alloc((size_t)N_NODES * 4);
  int* srcs    = (int*)alloc((size_t)(N_NODES + N_EDGES) * 4);
  int* bsum    = (int*)alloc(256 * 4);

  const int NB = (N_NODES + 255) / 256;  // 196
  // CSR build (dst-sorted incoming edges, self-loops included)
  k_init_cnt<<<NB, 256, 0, stream>>>(cnt);
  k_count<<<(N_EDGES + 255) / 256, 256, 0, stream>>>(ei + N_EDGES, cnt);
  k_scan_bsum<<<NB, 256, 0, stream>>>(cnt, bsum);
  k_scan_offsets<<<1, 256, 0, stream>>>(bsum, NB);
  k_scan_write<<<NB, 256, 0, stream>>>(cnt, bsum, rowptr, fillptr);
  k_fill<<<(N_NODES + N_EDGES + 255) / 256, 256, 0, stream>>>(ei, ei + N_EDGES, fillptr, srcs);

  // residual = x @ res_W + res_b
  k_gemm<<<dim3(782, 4), 256, 0, stream>>>(x, resW, resb, Rr, N_NODES, 128);

  const float* in = x;
  int K = 128;
  for (int L = 0; L < 3; L++) {
    k_gemm<<<dim3(782, 4), 256, 0, stream>>>(in, gW[L], nullptr, X0, N_NODES, K);
    k_att<<<N_NODES / 4, 256, 0, stream>>>(X0, gasrc[L], gadst[L], as_, ad_);
    k_agg<<<N_NODES / 4, 256, 0, stream>>>(rowptr, srcs, as_, ad_, X0, gbias[L], X1);
    hipMemsetAsync(stats, 0, 512 * 4, stream);
    k_bn_stats<<<256, 256, 0, stream>>>(X1, stats);
    k_bn_relu<<<(N_NODES * HC) / 256, 256, 0, stream>>>(X1, stats, bng[L], bnb[L]);
    in = X1; K = 256;
  }
  k_final<<<N_NODES / 4, 256, 0, stream>>>(X1, Rr, eps, muW, mub, lvW, lvb,
                                           decW, decb, auxW, auxb, out);
}

// Round 2
// 985.170 us; speedup vs baseline: 1.4077x; 1.4077x over previous
//
#include <hip/hip_runtime.h>

#define N_NODES 50000
#define N_EDGES 600000
#define HC 256
#define NH 8

typedef short s8v __attribute__((ext_vector_type(8)));
typedef float f4v __attribute__((ext_vector_type(4)));

__device__ inline ushort f2bf(float f) {
  unsigned u = __float_as_uint(f);
  unsigned r = u + 0x7FFF + ((u >> 16) & 1);  // RNE
  return (ushort)(r >> 16);
}

// ---------------------------------------------------------------- CSR build
__global__ void k_init_cnt(int* __restrict__ cnt) {
  int i = blockIdx.x * 256 + threadIdx.x;
  if (i < N_NODES) cnt[i] = 1;  // self-loop
}

__global__ void k_count(const int* __restrict__ dstE, int* __restrict__ cnt) {
  int e = blockIdx.x * 256 + threadIdx.x;
  if (e < N_EDGES) atomicAdd(&cnt[dstE[e]], 1);
}

__global__ void k_scan_bsum(const int* __restrict__ cnt, int* __restrict__ bsum) {
  __shared__ int sd[256];
  int i = blockIdx.x * 256 + threadIdx.x;
  sd[threadIdx.x] = (i < N_NODES) ? cnt[i] : 0;
  __syncthreads();
  for (int o = 128; o > 0; o >>= 1) {
    if (threadIdx.x < o) sd[threadIdx.x] += sd[threadIdx.x + o];
    __syncthreads();
  }
  if (threadIdx.x == 0) bsum[blockIdx.x] = sd[0];
}

__global__ void k_scan_offsets(int* __restrict__ bsum, int nb) {
  __shared__ int s[256];
  int t = threadIdx.x;
  int v = (t < nb) ? bsum[t] : 0;
  s[t] = v; __syncthreads();
  for (int o = 1; o < 256; o <<= 1) {
    int x = (t >= o) ? s[t - o] : 0;
    __syncthreads();
    s[t] += x;
    __syncthreads();
  }
  if (t < nb) bsum[t] = s[t] - v;  // exclusive
}

__global__ void k_scan_write(const int* __restrict__ cnt, const int* __restrict__ bsum,
                             int* __restrict__ rowptr, int* __restrict__ fillptr) {
  __shared__ int s[256];
  int t = threadIdx.x;
  int i = blockIdx.x * 256 + t;
  int v = (i < N_NODES) ? cnt[i] : 0;
  s[t] = v; __syncthreads();
  for (int o = 1; o < 256; o <<= 1) {
    int x = (t >= o) ? s[t - o] : 0;
    __syncthreads();
    s[t] += x;
    __syncthreads();
  }
  int excl = s[t] - v + bsum[blockIdx.x];
  if (i < N_NODES) {
    rowptr[i] = excl;
    fillptr[i] = excl;
    if (i == N_NODES - 1) rowptr[N_NODES] = excl + v;
  }
}

__global__ void k_fill(const int* __restrict__ srcE, const int* __restrict__ dstE,
                       int* __restrict__ fillptr, int* __restrict__ srcs) {
  int i = blockIdx.x * 256 + threadIdx.x;
  if (i < N_NODES) {
    int pos = atomicAdd(&fillptr[i], 1);
    srcs[pos] = i;                       // self-loop
  } else if (i < N_NODES + N_EDGES) {
    int e = i - N_NODES;
    int pos = atomicAdd(&fillptr[dstE[e]], 1);
    srcs[pos] = srcE[e];
  }
}

// ---------------------------------------------------------------- fp32 -> bf16 converts
__global__ void k_cvt_x(const float* __restrict__ X, ushort* __restrict__ Xb) {
  size_t i = ((size_t)blockIdx.x * 256 + threadIdx.x) * 4;
  float4 x4 = *(const float4*)&X[i];
  ushort4 o;
  o.x = f2bf(x4.x); o.y = f2bf(x4.y); o.z = f2bf(x4.z); o.w = f2bf(x4.w);
  *(ushort4*)&Xb[i] = o;
}

// W[K][Nw] fp32 -> Wt[Nw][K] bf16 (transpose + convert)
__global__ void k_cvt_wt(const float* __restrict__ W, ushort* __restrict__ Wt, int K, int Nw) {
  __shared__ ushort s[32][33];
  int tx = threadIdx.x & 31, ty = threadIdx.x >> 5;
  int k0 = blockIdx.x * 32, n0 = blockIdx.y * 32;
  for (int j = 0; j < 32; j += 8)
    s[ty + j][tx] = f2bf(W[(size_t)(k0 + ty + j) * Nw + n0 + tx]);
  __syncthreads();
  for (int j = 0; j < 32; j += 8)
    Wt[(size_t)(n0 + ty + j) * K + k0 + tx] = s[tx][ty + j];
}

// pack [muW | lvW | auxW | 0] -> Wth[128][256] bf16 (row n = output, k contiguous)
__global__ void k_pack_head(const float* __restrict__ muW, const float* __restrict__ lvW,
                            const float* __restrict__ auxW, ushort* __restrict__ Wth) {
  int n = blockIdx.x;   // 0..127
  int k = threadIdx.x;  // 0..255
  float v = 0.f;
  if (n < 32) v = muW[k * 32 + n];
  else if (n < 64) v = lvW[k * 32 + (n - 32)];
  else if (n < 94) v = auxW[k * 30 + (n - 64)];
  Wth[n * 256 + k] = f2bf(v);
}

// ---------------------------------------------------------------- bf16 MFMA GEMM
// A: bf16 [M][K] row-major. Wt: bf16 [N][K] (i.e. B transposed, k contiguous).
// Block tile 128(M) x 64(N); wave w owns m-tiles 2w,2w+1. K-tile 64.
// LDS stored in fragment order: block (mt*2+ks) of 64 lanes x 16B -> conflict-free b128.
__launch_bounds__(256)
__global__ void k_gemm_bf16(const ushort* __restrict__ A, const ushort* __restrict__ Wt,
                            const float* __restrict__ bias, float* __restrict__ Out,
                            int M, int K, int ldc) {
  __shared__ __align__(16) ushort As[16 * 64 * 8];  // 16 KB
  __shared__ __align__(16) ushort Bs[8 * 64 * 8];   //  8 KB
  int t = threadIdx.x;
  int w = t >> 6, L = t & 63;
  int bm = blockIdx.x * 128;
  int bn = blockIdx.y * 64;
  f4v zero = {0.f, 0.f, 0.f, 0.f};
  f4v acc[2][4];
#pragma unroll
  for (int mi = 0; mi < 2; mi++)
#pragma unroll
    for (int nt = 0; nt < 4; nt++) acc[mi][nt] = zero;

  for (int k0 = 0; k0 < K; k0 += 64) {
    // stage A: 128 rows x 64 bf16 = 1024 chunks of 8 bf16
#pragma unroll
    for (int u = 0; u < 4; u++) {
      int ci = t + u * 256;
      int r = ci >> 3, c = ci & 7;
      int row = bm + r;
      uint4 v = make_uint4(0, 0, 0, 0);
      if (row < M) v = *(const uint4*)&A[(size_t)row * K + k0 + c * 8];
      int mt = r >> 4, m = r & 15, ks = c >> 2, q = c & 3;
      *(uint4*)&As[(((mt * 2 + ks) * 64) + q * 16 + m) * 8] = v;
    }
    // stage B: 64 n-rows x 64 bf16 = 512 chunks
#pragma unroll
    for (int u = 0; u < 2; u++) {
      int ci = t + u * 256;
      int n = ci >> 3, c = ci & 7;
      uint4 v = *(const uint4*)&Wt[(size_t)(bn + n) * K + k0 + c * 8];
      int nt = n >> 4, nn = n & 15, ks = c >> 2, q = c & 3;
      *(uint4*)&Bs[(((nt * 2 + ks) * 64) + q * 16 + nn) * 8] = v;
    }
    __syncthreads();
#pragma unroll
    for (int ks = 0; ks < 2; ks++) {
      s8v a0 = *(const s8v*)&As[(((w * 2 + 0) * 2 + ks) * 64 + L) * 8];
      s8v a1 = *(const s8v*)&As[(((w * 2 + 1) * 2 + ks) * 64 + L) * 8];
#pragma unroll
      for (int nt = 0; nt < 4; nt++) {
        s8v b = *(const s8v*)&Bs[((nt * 2 + ks) * 64 + L) * 8];
        acc[0][nt] = __builtin_amdgcn_mfma_f32_16x16x32_bf16(a0, b, acc[0][nt], 0, 0, 0);
        acc[1][nt] = __builtin_amdgcn_mfma_f32_16x16x32_bf16(a1, b, acc[1][nt], 0, 0, 0);
      }
    }
    __syncthreads();
  }
  // epilogue: C/D layout col=lane&15, row=(lane>>4)*4+i
#pragma unroll
  for (int mi = 0; mi < 2; mi++) {
    int rbase = bm + (w * 2 + mi) * 16 + (L >> 4) * 4;
#pragma unroll
    for (int nt = 0; nt < 4; nt++) {
      int col = bn + nt * 16 + (L & 15);
      float bb = bias ? bias[col] : 0.f;
#pragma unroll
      for (int i = 0; i < 4; i++) {
        int r = rbase + i;
        if (r < M) Out[(size_t)r * ldc + col] = acc[mi][nt][i] + bb;
      }
    }
  }
}

// ---------------------------------------------------------------- attention logits a_s, a_d
__launch_bounds__(256)
__global__ void k_att(const float* __restrict__ B, const float* __restrict__ asrc,
                      const float* __restrict__ adst,
                      float* __restrict__ as_, float* __restrict__ ad_) {
  int wid = (blockIdx.x * 256 + threadIdx.x) >> 6;  // node
  int lane = threadIdx.x & 63;
  float4 h4 = *(const float4*)&B[(size_t)wid * 256 + (lane << 2)];
  float4 s4 = *(const float4*)&asrc[lane << 2];
  float4 d4 = *(const float4*)&adst[lane << 2];
  float vs = h4.x * s4.x + h4.y * s4.y + h4.z * s4.z + h4.w * s4.w;
  float vd = h4.x * d4.x + h4.y * d4.y + h4.z * d4.z + h4.w * d4.w;
  vs += __shfl_xor(vs, 1); vs += __shfl_xor(vs, 2); vs += __shfl_xor(vs, 4);
  vd += __shfl_xor(vd, 1); vd += __shfl_xor(vd, 2); vd += __shfl_xor(vd, 4);
  if ((lane & 7) == 0) {
    as_[wid * NH + (lane >> 3)] = vs;
    ad_[wid * NH + (lane >> 3)] = vd;
  }
}

// ---------------------------------------------------------------- softmax + aggregate (one wave / node)
__launch_bounds__(256)
__global__ void k_agg(const int* __restrict__ rowptr, const int* __restrict__ srcs,
                      const float* __restrict__ as_, const float* __restrict__ ad_,
                      const float* __restrict__ B, const float* __restrict__ gb,
                      float* __restrict__ C) {
  int n = (blockIdx.x * 256 + threadIdx.x) >> 6;
  int lane = threadIdx.x & 63;
  int beg = rowptr[n], end = rowptr[n + 1];
  int h = lane >> 3, j = lane & 7;
  float ad_nh = ad_[n * NH + h];
  float mx = -1e30f;
  for (int k = beg + j; k < end; k += 8) {
    int s = srcs[k];
    float e = as_[s * NH + h] + ad_nh;
    e = e > 0.f ? e : 0.2f * e;
    mx = fmaxf(mx, e);
  }
  mx = fmaxf(mx, __shfl_xor(mx, 1));
  mx = fmaxf(mx, __shfl_xor(mx, 2));
  mx = fmaxf(mx, __shfl_xor(mx, 4));
  float sum = 0.f;
  for (int k = beg + j; k < end; k += 8) {
    int s = srcs[k];
    float e = as_[s * NH + h] + ad_nh;
    e = e > 0.f ? e : 0.2f * e;
    sum += __expf(e - mx);
  }
  sum += __shfl_xor(sum, 1); sum += __shfl_xor(sum, 2); sum += __shfl_xor(sum, 4);
  float inv = 1.f / (sum + 1e-16f);
  float4 acc = make_float4(0.f, 0.f, 0.f, 0.f);
  for (int k = beg; k < end; k++) {
    int s = srcs[k];
    float e = as_[s * NH + h] + ad_nh;
    e = e > 0.f ? e : 0.2f * e;
    float alpha = __expf(e - mx) * inv;
    float4 b4 = *(const float4*)&B[(size_t)s * 256 + (lane << 2)];
    acc.x += alpha * b4.x; acc.y += alpha * b4.y;
    acc.z += alpha * b4.z; acc.w += alpha * b4.w;
  }
  float4 g4 = *(const float4*)&gb[lane << 2];
  acc.x += g4.x; acc.y += g4.y; acc.z += g4.z; acc.w += g4.w;
  *(float4*)&C[(size_t)n * 256 + (lane << 2)] = acc;
}

// ---------------------------------------------------------------- batch norm
__global__ void k_bn_stats(const float* __restrict__ X, float* __restrict__ stats) {
  int c = threadIdx.x;
  float s = 0.f, s2 = 0.f;
  for (int r = blockIdx.x; r < N_NODES; r += gridDim.x) {
    float v = X[(size_t)r * 256 + c];
    s += v; s2 += v * v;
  }
  atomicAdd(&stats[c], s);
  atomicAdd(&stats[256 + c], s2);
}

// BN + ReLU (+ optional residual add) -> bf16 output only
__global__ void k_bn_relu_cvt(const float* __restrict__ X, const float* __restrict__ stats,
                              const float* __restrict__ g, const float* __restrict__ b,
                              const float* __restrict__ resid, ushort* __restrict__ Xb) {
  size_t i = ((size_t)blockIdx.x * 256 + threadIdx.x) * 4;
  int c = (int)(i & 255);
  const float invN = 1.f / (float)N_NODES;
  float4 x4 = *(const float4*)&X[i];
  float4 s4 = *(const float4*)&stats[c];
  float4 q4 = *(const float4*)&stats[256 + c];
  float4 g4 = *(const float4*)&g[c];
  float4 b4 = *(const float4*)&b[c];
  float m0 = s4.x * invN, m1 = s4.y * invN, m2 = s4.z * invN, m3 = s4.w * invN;
  float v0 = (x4.x - m0) * rsqrtf(q4.x * invN - m0 * m0 + 1e-5f) * g4.x + b4.x;
  float v1 = (x4.y - m1) * rsqrtf(q4.y * invN - m1 * m1 + 1e-5f) * g4.y + b4.y;
  float v2 = (x4.z - m2) * rsqrtf(q4.z * invN - m2 * m2 + 1e-5f) * g4.z + b4.z;
  float v3 = (x4.w - m3) * rsqrtf(q4.w * invN - m3 * m3 + 1e-5f) * g4.w + b4.w;
  v0 = v0 > 0.f ? v0 : 0.f; v1 = v1 > 0.f ? v1 : 0.f;
  v2 = v2 > 0.f ? v2 : 0.f; v3 = v3 > 0.f ? v3 : 0.f;
  if (resid) {
    float4 r4 = *(const float4*)&resid[i];
    v0 += r4.x; v1 += r4.y; v2 += r4.z; v3 += r4.w;
  }
  ushort4 o;
  o.x = f2bf(v0); o.y = f2bf(v1); o.z = f2bf(v2); o.w = f2bf(v3);
  *(ushort4*)&Xb[i] = o;
}

// ---------------------------------------------------------------- decode epilogue (one wave / node)
__launch_bounds__(256)
__global__ void k_dec(const float* __restrict__ Hd, const float* __restrict__ eps,
                      const float* __restrict__ mub, const float* __restrict__ lvb,
                      const float* __restrict__ auxb,
                      const float* __restrict__ decW, const float* __restrict__ decb,
                      float* __restrict__ out) {
  __shared__ float wsd[2048];   // decW [32][64]
  __shared__ float shz[4][32];
  int t = threadIdx.x;
  for (int i = t; i < 2048; i += 256) wsd[i] = decW[i];
  int w = t >> 6, lane = t & 63;
  int n = blockIdx.x * 4 + w;
  const float* hd = &Hd[(size_t)n * 128];
  if (lane < 32) {
    float mu = hd[lane] + mub[lane];
    float lv = hd[32 + lane] + lvb[lane];
    out[(size_t)N_NODES * 64 + (size_t)n * 32 + lane] = mu;
    out[(size_t)N_NODES * 96 + (size_t)n * 32 + lane] = lv;
    shz[w][lane] = mu + eps[(size_t)n * 32 + lane] * __expf(0.5f * lv);
  } else if (lane < 62) {
    int j = lane - 32;
    out[(size_t)N_NODES * 128 + (size_t)n * 30 + j] = hd[64 + j] + auxb[j];
  }
  __syncthreads();
  float o = decb[lane];
#pragma unroll 8
  for (int k = 0; k < 32; k++) o += shz[w][k] * wsd[k * 64 + lane];
  out[(size_t)n * 64 + lane] = o;
}

// ---------------------------------------------------------------- launch
extern "C" void kernel_launch(void* const* d_in, const int* in_sizes, int n_in,
                              void* d_out, int out_size, void* d_ws, size_t ws_size,
                              hipStream_t stream) {
  (void)in_sizes; (void)n_in; (void)out_size; (void)ws_size;
  const float* x    = (const float*)d_in[0];
  const float* eps  = (const float*)d_in[1];
  const int*   ei   = (const int*)d_in[2];
  const float* gW[3]    = {(const float*)d_in[3],  (const float*)d_in[9],  (const float*)d_in[15]};
  const float* gasrc[3] = {(const float*)d_in[4],  (const float*)d_in[10], (const float*)d_in[16]};
  const float* gadst[3] = {(const float*)d_in[5],  (const float*)d_in[11], (const float*)d_in[17]};
  const float* gbias[3] = {(const float*)d_in[6],  (const float*)d_in[12], (const float*)d_in[18]};
  const float* bng[3]   = {(const float*)d_in[7],  (const float*)d_in[13], (const float*)d_in[19]};
  const float* bnb[3]   = {(const float*)d_in[8],  (const float*)d_in[14], (const float*)d_in[20]};
  const float* resW = (const float*)d_in[21];
  const float* resb = (const float*)d_in[22];
  const float* muW  = (const float*)d_in[23];
  const float* mub  = (const float*)d_in[24];
  const float* lvW  = (const float*)d_in[25];
  const float* lvb  = (const float*)d_in[26];
  const float* decW = (const float*)d_in[27];
  const float* decb = (const float*)d_in[28];
  const float* auxW = (const float*)d_in[29];
  const float* auxb = (const float*)d_in[30];
  float* out = (float*)d_out;

  char* ws = (char*)d_ws;
  size_t off = 0;
  auto alloc = [&](size_t bytes) -> void* {
    void* p = ws + off;
    off += (bytes + 255) & ~(size_t)255;
    return p;
  };
  float*  X0    = (float*)alloc((size_t)N_NODES * HC * 4);   // GEMM out / att input; reused as Hd
  float*  X1    = (float*)alloc((size_t)N_NODES * HC * 4);   // agg output
  float*  Rr    = (float*)alloc((size_t)N_NODES * HC * 4);   // residual
  ushort* Xb    = (ushort*)alloc((size_t)N_NODES * HC * 2);  // bf16 activations
  float*  as_   = (float*)alloc((size_t)N_NODES * NH * 4);
  float*  ad_   = (float*)alloc((size_t)N_NODES * NH * 4);
  float*  stats = (float*)alloc(512 * 4);
  int* cnt      = (int*)alloc((size_t)N_NODES * 4);
  int* rowptr   = (int*)alloc((size_t)(N_NODES + 1) * 4);
  int* fillptr  = (int*)alloc((size_t)N_NODES * 4);
  int* srcs     = (int*)alloc((size_t)(N_NODES + N_EDGES) * 4);
  int* bsum     = (int*)alloc(256 * 4);
  ushort* Wt1   = (ushort*)alloc(256 * 128 * 2);
  ushort* Wt2   = (ushort*)alloc(256 * 256 * 2);
  ushort* Wt3   = (ushort*)alloc(256 * 256 * 2);
  ushort* WtR   = (ushort*)alloc(256 * 128 * 2);
  ushort* Wth   = (ushort*)alloc(128 * 256 * 2);
  float*  Hd    = X0;  // alias: X0 dead after layer-3 agg

  const int NB = (N_NODES + 255) / 256;
  // CSR build
  k_init_cnt<<<NB, 256, 0, stream>>>(cnt);
  k_count<<<(N_EDGES + 255) / 256, 256, 0, stream>>>(ei + N_EDGES, cnt);
  k_scan_bsum<<<NB, 256, 0, stream>>>(cnt, bsum);
  k_scan_offsets<<<1, 256, 0, stream>>>(bsum, NB);
  k_scan_write<<<NB, 256, 0, stream>>>(cnt, bsum, rowptr, fillptr);
  k_fill<<<(N_NODES + N_EDGES + 255) / 256, 256, 0, stream>>>(ei, ei + N_EDGES, fillptr, srcs);

  // weight prep
  k_cvt_wt<<<dim3(4, 8), 256, 0, stream>>>(gW[0], Wt1, 128, 256);
  k_cvt_wt<<<dim3(8, 8), 256, 0, stream>>>(gW[1], Wt2, 256, 256);
  k_cvt_wt<<<dim3(8, 8), 256, 0, stream>>>(gW[2], Wt3, 256, 256);
  k_cvt_wt<<<dim3(4, 8), 256, 0, stream>>>(resW, WtR, 128, 256);
  k_pack_head<<<128, 256, 0, stream>>>(muW, lvW, auxW, Wth);
  // x -> bf16
  k_cvt_x<<<(N_NODES * 128) / 1024, 256, 0, stream>>>(x, Xb);

  // residual = x @ res_W + res_b
  k_gemm_bf16<<<dim3(391, 4), 256, 0, stream>>>(Xb, WtR, resb, Rr, N_NODES, 128, 256);

  const ushort* Wts[3] = {Wt1, Wt2, Wt3};
  int K = 128;
  for (int L = 0; L < 3; L++) {
    k_gemm_bf16<<<dim3(391, 4), 256, 0, stream>>>(Xb, Wts[L], nullptr, X0, N_NODES, K, 256);
    k_att<<<N_NODES / 4, 256, 0, stream>>>(X0, gasrc[L], gadst[L], as_, ad_);
    k_agg<<<N_NODES / 4, 256, 0, stream>>>(rowptr, srcs, as_, ad_, X0, gbias[L], X1);
    hipMemsetAsync(stats, 0, 512 * 4, stream);
    k_bn_stats<<<256, 256, 0, stream>>>(X1, stats);
    k_bn_relu_cvt<<<(N_NODES * HC) / 1024, 256, 0, stream>>>(
        X1, stats, bng[L], bnb[L], (L == 2) ? Rr : nullptr, Xb);
    K = 256;
  }
  // heads: Hd = h @ [muW|lvW|auxW|0]
  k_gemm_bf16<<<dim3(391, 2), 256, 0, stream>>>(Xb, Wth, nullptr, Hd, N_NODES, 256, 128);
  k_dec<<<N_NODES / 4, 256, 0, stream>>>(Hd, eps, mub, lvb, auxb, decW, decb, out);
}

// Round 3
// 896.268 us; speedup vs baseline: 1.5473x; 1.0992x over previous
//
#include <hip/hip_runtime.h>

#define N_NODES 50000
#define N_EDGES 600000
#define HC 256
#define NH 8

typedef short s8v __attribute__((ext_vector_type(8)));
typedef float f4v __attribute__((ext_vector_type(4)));
typedef __attribute__((address_space(1))) const unsigned int as1_cu32;
typedef __attribute__((address_space(3))) unsigned int as3_u32;

__device__ inline ushort f2bf(float f) {
  unsigned u = __float_as_uint(f);
  unsigned r = u + 0x7FFF + ((u >> 16) & 1);  // RNE
  return (ushort)(r >> 16);
}

// ---------------------------------------------------------------- CSR build
__global__ void k_init_cnt(int* __restrict__ cnt) {
  int i = blockIdx.x * 256 + threadIdx.x;
  if (i < N_NODES) cnt[i] = 1;  // self-loop
}

__global__ void k_count(const int* __restrict__ dstE, int* __restrict__ cnt) {
  int e = blockIdx.x * 256 + threadIdx.x;
  if (e < N_EDGES) atomicAdd(&cnt[dstE[e]], 1);
}

__global__ void k_scan_bsum(const int* __restrict__ cnt, int* __restrict__ bsum) {
  __shared__ int sd[256];
  int i = blockIdx.x * 256 + threadIdx.x;
  sd[threadIdx.x] = (i < N_NODES) ? cnt[i] : 0;
  __syncthreads();
  for (int o = 128; o > 0; o >>= 1) {
    if (threadIdx.x < o) sd[threadIdx.x] += sd[threadIdx.x + o];
    __syncthreads();
  }
  if (threadIdx.x == 0) bsum[blockIdx.x] = sd[0];
}

__global__ void k_scan_offsets(int* __restrict__ bsum, int nb) {
  __shared__ int s[256];
  int t = threadIdx.x;
  int v = (t < nb) ? bsum[t] : 0;
  s[t] = v; __syncthreads();
  for (int o = 1; o < 256; o <<= 1) {
    int x = (t >= o) ? s[t - o] : 0;
    __syncthreads();
    s[t] += x;
    __syncthreads();
  }
  if (t < nb) bsum[t] = s[t] - v;  // exclusive
}

__global__ void k_scan_write(const int* __restrict__ cnt, const int* __restrict__ bsum,
                             int* __restrict__ rowptr, int* __restrict__ fillptr) {
  __shared__ int s[256];
  int t = threadIdx.x;
  int i = blockIdx.x * 256 + t;
  int v = (i < N_NODES) ? cnt[i] : 0;
  s[t] = v; __syncthreads();
  for (int o = 1; o < 256; o <<= 1) {
    int x = (t >= o) ? s[t - o] : 0;
    __syncthreads();
    s[t] += x;
    __syncthreads();
  }
  int excl = s[t] - v + bsum[blockIdx.x];
  if (i < N_NODES) {
    rowptr[i] = excl;
    fillptr[i] = excl;
    if (i == N_NODES - 1) rowptr[N_NODES] = excl + v;
  }
}

__global__ void k_fill(const int* __restrict__ srcE, const int* __restrict__ dstE,
                       int* __restrict__ fillptr, int* __restrict__ srcs) {
  int i = blockIdx.x * 256 + threadIdx.x;
  if (i < N_NODES) {
    int pos = atomicAdd(&fillptr[i], 1);
    srcs[pos] = i;                       // self-loop
  } else if (i < N_NODES + N_EDGES) {
    int e = i - N_NODES;
    int pos = atomicAdd(&fillptr[dstE[e]], 1);
    srcs[pos] = srcE[e];
  }
}

// ---------------------------------------------------------------- fp32 -> bf16 converts
__global__ void k_cvt_x(const float* __restrict__ X, ushort* __restrict__ Xb) {
  size_t i = ((size_t)blockIdx.x * 256 + threadIdx.x) * 4;
  float4 x4 = *(const float4*)&X[i];
  ushort4 o;
  o.x = f2bf(x4.x); o.y = f2bf(x4.y); o.z = f2bf(x4.z); o.w = f2bf(x4.w);
  *(ushort4*)&Xb[i] = o;
}

// W[K][Nw] fp32 -> Wt[Nw][K] bf16 (transpose + convert)
__global__ void k_cvt_wt(const float* __restrict__ W, ushort* __restrict__ Wt, int K, int Nw) {
  __shared__ ushort s[32][33];
  int tx = threadIdx.x & 31, ty = threadIdx.x >> 5;
  int k0 = blockIdx.x * 32, n0 = blockIdx.y * 32;
  for (int j = 0; j < 32; j += 8)
    s[ty + j][tx] = f2bf(W[(size_t)(k0 + ty + j) * Nw + n0 + tx]);
  __syncthreads();
  for (int j = 0; j < 32; j += 8)
    Wt[(size_t)(n0 + ty + j) * K + k0 + tx] = s[tx][ty + j];
}

// pack [muW | lvW | auxW | 0] -> Wth[128][256] bf16
__global__ void k_pack_head(const float* __restrict__ muW, const float* __restrict__ lvW,
                            const float* __restrict__ auxW, ushort* __restrict__ Wth) {
  int n = blockIdx.x;   // 0..127
  int k = threadIdx.x;  // 0..255
  float v = 0.f;
  if (n < 32) v = muW[k * 32 + n];
  else if (n < 64) v = lvW[k * 32 + (n - 32)];
  else if (n < 94) v = auxW[k * 30 + (n - 64)];
  Wth[n * 256 + k] = f2bf(v);
}

// ---------------------------------------------------------------- bf16 MFMA GEMM (m97-style)
// A: bf16 [M][K] row-major. Wt: bf16 [N][K]. Block tile 128x128, K-tile 64.
// LDS staged via global_load_lds width=16 directly in fragment order:
//   A block i=mt*2+ks (mt m-subtile 0..7, ks k-half): lane L holds
//   A[bm+mt*16+(L&15)][k0+ks*32+(L>>4)*8 ..+7]  == MFMA A-frag for that subtile.
__launch_bounds__(256)
__global__ void k_gemm_bf16(const ushort* __restrict__ A, const ushort* __restrict__ Wt,
                            const float* __restrict__ bias, float* __restrict__ Out,
                            int M, int K, int ldc) {
  __shared__ __align__(16) ushort As[16 * 512];  // 16 KB: 16 frag-blocks x 64 lanes x 8 bf16
  __shared__ __align__(16) ushort Bs[16 * 512];  // 16 KB
  int t = threadIdx.x, w = t >> 6, L = t & 63;
  int bm = blockIdx.x * 128, bn = blockIdx.y * 128;
  int lrow = L & 15, lcol = (L >> 4) * 8;

  const ushort* ga[4];
  const ushort* gb[4];
#pragma unroll
  for (int u = 0; u < 4; u++) {
    int i = w * 4 + u;            // block index 0..15 (this wave's share)
    int mt = i >> 1, ks = i & 1;  // same split for A (m-subtile) and B (n-subtile)
    int arow = bm + mt * 16 + lrow;
    if (arow >= M) arow = M - 1;  // clamp (last block); stores are guarded
    ga[u] = A + (size_t)arow * K + ks * 32 + lcol;
    int brow = bn + mt * 16 + lrow;
    gb[u] = Wt + (size_t)brow * K + ks * 32 + lcol;
  }

  f4v acc[4][4];
  f4v zero = {0.f, 0.f, 0.f, 0.f};
#pragma unroll
  for (int mi = 0; mi < 4; mi++)
#pragma unroll
    for (int ni = 0; ni < 4; ni++) acc[mi][ni] = zero;

  int wm = (w >> 1) * 4;  // this wave's m-subtile base (0 or 4)
  int wn = (w & 1) * 4;   // this wave's n-subtile base

  int nk = K >> 6;
  for (int kt = 0; kt < nk; kt++) {
#pragma unroll
    for (int u = 0; u < 4; u++) {
      int i = w * 4 + u;
      __builtin_amdgcn_global_load_lds((as1_cu32*)ga[u], (as3_u32*)&As[i * 512], 16, 0, 0);
      __builtin_amdgcn_global_load_lds((as1_cu32*)gb[u], (as3_u32*)&Bs[i * 512], 16, 0, 0);
      ga[u] += 64; gb[u] += 64;
    }
    __syncthreads();
#pragma unroll
    for (int ks = 0; ks < 2; ks++) {
      s8v af[4], bf[4];
#pragma unroll
      for (int mi = 0; mi < 4; mi++)
        af[mi] = *(const s8v*)&As[(((wm + mi) * 2 + ks) * 64 + L) * 8];
#pragma unroll
      for (int ni = 0; ni < 4; ni++)
        bf[ni] = *(const s8v*)&Bs[(((wn + ni) * 2 + ks) * 64 + L) * 8];
#pragma unroll
      for (int mi = 0; mi < 4; mi++)
#pragma unroll
        for (int ni = 0; ni < 4; ni++)
          acc[mi][ni] = __builtin_amdgcn_mfma_f32_16x16x32_bf16(af[mi], bf[ni], acc[mi][ni], 0, 0, 0);
    }
    __syncthreads();
  }
  // epilogue: C/D layout col=lane&15, row=(lane>>4)*4+i
#pragma unroll
  for (int ni = 0; ni < 4; ni++) {
    int col = bn + (wn + ni) * 16 + (L & 15);
    float bb = bias ? bias[col] : 0.f;
#pragma unroll
    for (int mi = 0; mi < 4; mi++) {
      int rbase = bm + (wm + mi) * 16 + (L >> 4) * 4;
#pragma unroll
      for (int i = 0; i < 4; i++) {
        int r = rbase + i;
        if (r < M) Out[(size_t)r * ldc + col] = acc[mi][ni][i] + bb;
      }
    }
  }
}

// ---------------------------------------------------------------- attention logits a_s, a_d
__launch_bounds__(256)
__global__ void k_att(const float* __restrict__ B, const float* __restrict__ asrc,
                      const float* __restrict__ adst,
                      float* __restrict__ as_, float* __restrict__ ad_) {
  int wid = (blockIdx.x * 256 + threadIdx.x) >> 6;  // node
  int lane = threadIdx.x & 63;
  float4 h4 = *(const float4*)&B[(size_t)wid * 256 + (lane << 2)];
  float4 s4 = *(const float4*)&asrc[lane << 2];
  float4 d4 = *(const float4*)&adst[lane << 2];
  float vs = h4.x * s4.x + h4.y * s4.y + h4.z * s4.z + h4.w * s4.w;
  float vd = h4.x * d4.x + h4.y * d4.y + h4.z * d4.z + h4.w * d4.w;
  vs += __shfl_xor(vs, 1); vs += __shfl_xor(vs, 2); vs += __shfl_xor(vs, 4);
  vd += __shfl_xor(vd, 1); vd += __shfl_xor(vd, 2); vd += __shfl_xor(vd, 4);
  if ((lane & 7) == 0) {
    as_[wid * NH + (lane >> 3)] = vs;
    ad_[wid * NH + (lane >> 3)] = vd;
  }
}

// ---------------------------------------------------------------- softmax + aggregate (one wave / node)
// online softmax (single logits pass) + unroll-4 gather for memory-level parallelism
__launch_bounds__(256)
__global__ void k_agg(const int* __restrict__ rowptr, const int* __restrict__ srcs,
                      const float* __restrict__ as_, const float* __restrict__ ad_,
                      const float* __restrict__ B, const float* __restrict__ gb,
                      float* __restrict__ C) {
  int n = (blockIdx.x * 256 + threadIdx.x) >> 6;
  int lane = threadIdx.x & 63;
  int beg = rowptr[n], end = rowptr[n + 1];
  int h = lane >> 3, j = lane & 7;
  float ad_nh = ad_[n * NH + h];
  // online max+sum, 8 j-lanes strided
  float mx = -1e30f, sm = 0.f;
  for (int k = beg + j; k < end; k += 8) {
    int s = srcs[k];
    float e = as_[s * NH + h] + ad_nh;
    e = e > 0.f ? e : 0.2f * e;
    float m2 = fmaxf(mx, e);
    sm = sm * __expf(mx - m2) + __expf(e - m2);
    mx = m2;
  }
#pragma unroll
  for (int o = 1; o <= 4; o <<= 1) {
    float mo = __shfl_xor(mx, o);
    float so = __shfl_xor(sm, o);
    float m2 = fmaxf(mx, mo);
    sm = sm * __expf(mx - m2) + so * __expf(mo - m2);
    mx = m2;
  }
  float inv = 1.f / (sm + 1e-16f);
  // gather, unrolled x4: 4 independent row loads in flight
  float4 acc = make_float4(0.f, 0.f, 0.f, 0.f);
  int k = beg;
  for (; k + 4 <= end; k += 4) {
    int s0 = srcs[k], s1 = srcs[k + 1], s2 = srcs[k + 2], s3 = srcs[k + 3];
    float4 b0 = *(const float4*)&B[(size_t)s0 * 256 + (lane << 2)];
    float4 b1 = *(const float4*)&B[(size_t)s1 * 256 + (lane << 2)];
    float4 b2 = *(const float4*)&B[(size_t)s2 * 256 + (lane << 2)];
    float4 b3 = *(const float4*)&B[(size_t)s3 * 256 + (lane << 2)];
    float e0 = as_[s0 * NH + h] + ad_nh; e0 = e0 > 0.f ? e0 : 0.2f * e0;
    float e1 = as_[s1 * NH + h] + ad_nh; e1 = e1 > 0.f ? e1 : 0.2f * e1;
    float e2 = as_[s2 * NH + h] + ad_nh; e2 = e2 > 0.f ? e2 : 0.2f * e2;
    float e3 = as_[s3 * NH + h] + ad_nh; e3 = e3 > 0.f ? e3 : 0.2f * e3;
    float a0 = __expf(e0 - mx) * inv;
    float a1 = __expf(e1 - mx) * inv;
    float a2 = __expf(e2 - mx) * inv;
    float a3 = __expf(e3 - mx) * inv;
    acc.x += a0 * b0.x + a1 * b1.x + a2 * b2.x + a3 * b3.x;
    acc.y += a0 * b0.y + a1 * b1.y + a2 * b2.y + a3 * b3.y;
    acc.z += a0 * b0.z + a1 * b1.z + a2 * b2.z + a3 * b3.z;
    acc.w += a0 * b0.w + a1 * b1.w + a2 * b2.w + a3 * b3.w;
  }
  for (; k < end; k++) {
    int s = srcs[k];
    float e = as_[s * NH + h] + ad_nh;
    e = e > 0.f ? e : 0.2f * e;
    float alpha = __expf(e - mx) * inv;
    float4 b4 = *(const float4*)&B[(size_t)s * 256 + (lane << 2)];
    acc.x += alpha * b4.x; acc.y += alpha * b4.y;
    acc.z += alpha * b4.z; acc.w += alpha * b4.w;
  }
  float4 g4 = *(const float4*)&gb[lane << 2];
  acc.x += g4.x; acc.y += g4.y; acc.z += g4.z; acc.w += g4.w;
  *(float4*)&C[(size_t)n * 256 + (lane << 2)] = acc;
}

// ---------------------------------------------------------------- batch norm
__global__ void k_bn_stats(const float* __restrict__ X, float* __restrict__ stats) {
  int c = threadIdx.x;
  float s = 0.f, s2 = 0.f;
  for (int r = blockIdx.x; r < N_NODES; r += gridDim.x) {
    float v = X[(size_t)r * 256 + c];
    s += v; s2 += v * v;
  }
  atomicAdd(&stats[c], s);
  atomicAdd(&stats[256 + c], s2);
}

// BN + ReLU (+ optional residual add) -> bf16 output only
__global__ void k_bn_relu_cvt(const float* __restrict__ X, const float* __restrict__ stats,
                              const float* __restrict__ g, const float* __restrict__ b,
                              const float* __restrict__ resid, ushort* __restrict__ Xb) {
  size_t i = ((size_t)blockIdx.x * 256 + threadIdx.x) * 4;
  int c = (int)(i & 255);
  const float invN = 1.f / (float)N_NODES;
  float4 x4 = *(const float4*)&X[i];
  float4 s4 = *(const float4*)&stats[c];
  float4 q4 = *(const float4*)&stats[256 + c];
  float4 g4 = *(const float4*)&g[c];
  float4 b4 = *(const float4*)&b[c];
  float m0 = s4.x * invN, m1 = s4.y * invN, m2 = s4.z * invN, m3 = s4.w * invN;
  float v0 = (x4.x - m0) * rsqrtf(q4.x * invN - m0 * m0 + 1e-5f) * g4.x + b4.x;
  float v1 = (x4.y - m1) * rsqrtf(q4.y * invN - m1 * m1 + 1e-5f) * g4.y + b4.y;
  float v2 = (x4.z - m2) * rsqrtf(q4.z * invN - m2 * m2 + 1e-5f) * g4.z + b4.z;
  float v3 = (x4.w - m3) * rsqrtf(q4.w * invN - m3 * m3 + 1e-5f) * g4.w + b4.w;
  v0 = v0 > 0.f ? v0 : 0.f; v1 = v1 > 0.f ? v1 : 0.f;
  v2 = v2 > 0.f ? v2 : 0.f; v3 = v3 > 0.f ? v3 : 0.f;
  if (resid) {
    float4 r4 = *(const float4*)&resid[i];
    v0 += r4.x; v1 += r4.y; v2 += r4.z; v3 += r4.w;
  }
  ushort4 o;
  o.x = f2bf(v0); o.y = f2bf(v1); o.z = f2bf(v2); o.w = f2bf(v3);
  *(ushort4*)&Xb[i] = o;
}

// ---------------------------------------------------------------- decode epilogue (one wave / node)
__launch_bounds__(256)
__global__ void k_dec(const float* __restrict__ Hd, const float* __restrict__ eps,
                      const float* __restrict__ mub, const float* __restrict__ lvb,
                      const float* __restrict__ auxb,
                      const float* __restrict__ decW, const float* __restrict__ decb,
                      float* __restrict__ out) {
  __shared__ float wsd[2048];   // decW [32][64]
  __shared__ float shz[4][32];
  int t = threadIdx.x;
  for (int i = t; i < 2048; i += 256) wsd[i] = decW[i];
  int w = t >> 6, lane = t & 63;
  int n = blockIdx.x * 4 + w;
  const float* hd = &Hd[(size_t)n * 128];
  if (lane < 32) {
    float mu = hd[lane] + mub[lane];
    float lv = hd[32 + lane] + lvb[lane];
    out[(size_t)N_NODES * 64 + (size_t)n * 32 + lane] = mu;
    out[(size_t)N_NODES * 96 + (size_t)n * 32 + lane] = lv;
    shz[w][lane] = mu + eps[(size_t)n * 32 + lane] * __expf(0.5f * lv);
  } else if (lane < 62) {
    int j = lane - 32;
    out[(size_t)N_NODES * 128 + (size_t)n * 30 + j] = hd[64 + j] + auxb[j];
  }
  __syncthreads();
  float o = decb[lane];
#pragma unroll 8
  for (int k = 0; k < 32; k++) o += shz[w][k] * wsd[k * 64 + lane];
  out[(size_t)n * 64 + lane] = o;
}

// ---------------------------------------------------------------- launch
extern "C" void kernel_launch(void* const* d_in, const int* in_sizes, int n_in,
                              void* d_out, int out_size, void* d_ws, size_t ws_size,
                              hipStream_t stream) {
  (void)in_sizes; (void)n_in; (void)out_size; (void)ws_size;
  const float* x    = (const float*)d_in[0];
  const float* eps  = (const float*)d_in[1];
  const int*   ei   = (const int*)d_in[2];
  const float* gW[3]    = {(const float*)d_in[3],  (const float*)d_in[9],  (const float*)d_in[15]};
  const float* gasrc[3] = {(const float*)d_in[4],  (const float*)d_in[10], (const float*)d_in[16]};
  const float* gadst[3] = {(const float*)d_in[5],  (const float*)d_in[11], (const float*)d_in[17]};
  const float* gbias[3] = {(const float*)d_in[6],  (const float*)d_in[12], (const float*)d_in[18]};
  const float* bng[3]   = {(const float*)d_in[7],  (const float*)d_in[13], (const float*)d_in[19]};
  const float* bnb[3]   = {(const float*)d_in[8],  (const float*)d_in[14], (const float*)d_in[20]};
  const float* resW = (const float*)d_in[21];
  const float* resb = (const float*)d_in[22];
  const float* muW  = (const float*)d_in[23];
  const float* mub  = (const float*)d_in[24];
  const float* lvW  = (const float*)d_in[25];
  const float* lvb  = (const float*)d_in[26];
  const float* decW = (const float*)d_in[27];
  const float* decb = (const float*)d_in[28];
  const float* auxW = (const float*)d_in[29];
  const float* auxb = (const float*)d_in[30];
  float* out = (float*)d_out;

  char* ws = (char*)d_ws;
  size_t off = 0;
  auto alloc = [&](size_t bytes) -> void* {
    void* p = ws + off;
    off += (bytes + 255) & ~(size_t)255;
    return p;
  };
  float*  X0    = (float*)alloc((size_t)N_NODES * HC * 4);   // GEMM out / att input; reused as Hd
  float*  X1    = (float*)alloc((size_t)N_NODES * HC * 4);   // agg output
  float*  Rr    = (float*)alloc((size_t)N_NODES * HC * 4);   // residual
  ushort* Xb    = (ushort*)alloc((size_t)N_NODES * HC * 2);  // bf16 activations
  float*  as_   = (float*)alloc((size_t)N_NODES * NH * 4);
  float*  ad_   = (float*)alloc((size_t)N_NODES * NH * 4);
  float*  stats = (float*)alloc(512 * 4);
  int* cnt      = (int*)alloc((size_t)N_NODES * 4);
  int* rowptr   = (int*)alloc((size_t)(N_NODES + 1) * 4);
  int* fillptr  = (int*)alloc((size_t)N_NODES * 4);
  int* srcs     = (int*)alloc((size_t)(N_NODES + N_EDGES) * 4);
  int* bsum     = (int*)alloc(256 * 4);
  ushort* Wt1   = (ushort*)alloc(256 * 128 * 2);
  ushort* Wt2   = (ushort*)alloc(256 * 256 * 2);
  ushort* Wt3   = (ushort*)alloc(256 * 256 * 2);
  ushort* WtR   = (ushort*)alloc(256 * 128 * 2);
  ushort* Wth   = (ushort*)alloc(128 * 256 * 2);
  float*  Hd    = X0;  // alias: X0 dead after layer-3 agg

  const int NB = (N_NODES + 255) / 256;
  // CSR build
  k_init_cnt<<<NB, 256, 0, stream>>>(cnt);
  k_count<<<(N_EDGES + 255) / 256, 256, 0, stream>>>(ei + N_EDGES, cnt);
  k_scan_bsum<<<NB, 256, 0, stream>>>(cnt, bsum);
  k_scan_offsets<<<1, 256, 0, stream>>>(bsum, NB);
  k_scan_write<<<NB, 256, 0, stream>>>(cnt, bsum, rowptr, fillptr);
  k_fill<<<(N_NODES + N_EDGES + 255) / 256, 256, 0, stream>>>(ei, ei + N_EDGES, fillptr, srcs);

  // weight prep
  k_cvt_wt<<<dim3(4, 8), 256, 0, stream>>>(gW[0], Wt1, 128, 256);
  k_cvt_wt<<<dim3(8, 8), 256, 0, stream>>>(gW[1], Wt2, 256, 256);
  k_cvt_wt<<<dim3(8, 8), 256, 0, stream>>>(gW[2], Wt3, 256, 256);
  k_cvt_wt<<<dim3(4, 8), 256, 0, stream>>>(resW, WtR, 128, 256);
  k_pack_head<<<128, 256, 0, stream>>>(muW, lvW, auxW, Wth);
  // x -> bf16
  k_cvt_x<<<(N_NODES * 128) / 1024, 256, 0, stream>>>(x, Xb);

  const int GM = (N_NODES + 127) / 128;  // 391
  // residual = x @ res_W + res_b
  k_gemm_bf16<<<dim3(GM, 2), 256, 0, stream>>>(Xb, WtR, resb, Rr, N_NODES, 128, 256);

  const ushort* Wts[3] = {Wt1, Wt2, Wt3};
  int K = 128;
  for (int L = 0; L < 3; L++) {
    k_gemm_bf16<<<dim3(GM, 2), 256, 0, stream>>>(Xb, Wts[L], nullptr, X0, N_NODES, K, 256);
    k_att<<<N_NODES / 4, 256, 0, stream>>>(X0, gasrc[L], gadst[L], as_, ad_);
    k_agg<<<N_NODES / 4, 256, 0, stream>>>(rowptr, srcs, as_, ad_, X0, gbias[L], X1);
    hipMemsetAsync(stats, 0, 512 * 4, stream);
    k_bn_stats<<<1024, 256, 0, stream>>>(X1, stats);
    k_bn_relu_cvt<<<(N_NODES * HC) / 1024, 256, 0, stream>>>(
        X1, stats, bng[L], bnb[L], (L == 2) ? Rr : nullptr, Xb);
    K = 256;
  }
  // heads: Hd = h @ [muW|lvW|auxW|0]
  k_gemm_bf16<<<dim3(GM, 1), 256, 0, stream>>>(Xb, Wth, nullptr, Hd, N_NODES, 256, 128);
  k_dec<<<N_NODES / 4, 256, 0, stream>>>(Hd, eps, mub, lvb, auxb, decW, decb, out);
}